// Round 1
// baseline (4140.844 us; speedup 1.0000x reference)
//
#include <hip/hip_runtime.h>
#include <hip/hip_fp16.h>

typedef _Float16 half2_t __attribute__((ext_vector_type(2)));
typedef _Float16 half4_t __attribute__((ext_vector_type(4)));
typedef _Float16 half8_t __attribute__((ext_vector_type(8)));
typedef float floatx4 __attribute__((ext_vector_type(4)));

#define B_   32
#define S_   512
#define D_   768
#define H_   384
#define H3_  1152      // 3*H
#define M_   (B_*S_)   // 16384
#define N2_  (2*H3_)   // 2304
#define TWOH_ 768

// ---------------- generic fp32 -> fp16 convert (vec4) ----------------
__global__ void cvt_f32_f16_kernel(const float* __restrict__ src,
                                   _Float16* __restrict__ dst, int n4) {
  int i = blockIdx.x * blockDim.x + threadIdx.x;
  if (i >= n4) return;
  float4 v = ((const float4*)src)[i];
  half4_t h = {(_Float16)v.x, (_Float16)v.y, (_Float16)v.z, (_Float16)v.w};
  ((half4_t*)dst)[i] = h;
}

// ---------------- pack W_hh -> [dir][k8][n][8] fp16 ----------------
__global__ void pack_whh_kernel(const float* __restrict__ Wf,
                                const float* __restrict__ Wb,
                                _Float16* __restrict__ dst) {
  int idx = blockIdx.x * blockDim.x + threadIdx.x;
  if (idx >= 2 * H3_ * H_) return;
  int dir = idx / (H3_ * H_);
  int rem = idx - dir * (H3_ * H_);
  int j  = rem & 7;
  int t  = rem >> 3;          // k8*1152 + n
  int n  = t % H3_;
  int k8 = t / H3_;
  const float* W = dir ? Wb : Wf;
  dst[idx] = (_Float16)W[n * H_ + k8 * 8 + j];
}

// ---------------- input-projection GEMM (fp16 MFMA) ----------------
// A: ip16 [16384][768], B: Wih16 [2304][768]  ->  xw [2][512][32][1152] fp16
__global__ __launch_bounds__(256) void gemm_xw_kernel(
    const _Float16* __restrict__ A, const _Float16* __restrict__ Bm,
    const float* __restrict__ bias_f, const float* __restrict__ bias_b,
    _Float16* __restrict__ xw) {
  __shared__ _Float16 As[64][40];
  __shared__ _Float16 Bs[64][40];
  const int m0 = blockIdx.x * 64, n0 = blockIdx.y * 64;
  const int tid = threadIdx.x, lane = tid & 63, w = tid >> 6;
  const int wm = w >> 1, wn = w & 1;
  const int q = lane >> 4, c = lane & 15;
  floatx4 acc[2][2] = {};

  const int t = tid & 127;
  const int srow = t >> 1, skh = (t & 1) * 16;
  const _Float16* gsrc =
      (tid < 128 ? A + (size_t)(m0 + srow) * D_ : Bm + (size_t)(n0 + srow) * D_) + skh;
  _Float16* ldst = (tid < 128) ? &As[srow][skh] : &Bs[srow][skh];

  for (int k0 = 0; k0 < D_; k0 += 32) {
    half8_t v0 = *(const half8_t*)(gsrc + k0);
    half8_t v1 = *(const half8_t*)(gsrc + k0 + 8);
    __syncthreads();
    *(half8_t*)ldst = v0;
    *(half8_t*)(ldst + 8) = v1;
    __syncthreads();
    half8_t a0 = *(const half8_t*)&As[wm * 32 + c][q * 8];
    half8_t a1 = *(const half8_t*)&As[wm * 32 + 16 + c][q * 8];
    half8_t b0 = *(const half8_t*)&Bs[wn * 32 + c][q * 8];
    half8_t b1 = *(const half8_t*)&Bs[wn * 32 + 16 + c][q * 8];
    acc[0][0] = __builtin_amdgcn_mfma_f32_16x16x32_f16(a0, b0, acc[0][0], 0, 0, 0);
    acc[0][1] = __builtin_amdgcn_mfma_f32_16x16x32_f16(a0, b1, acc[0][1], 0, 0, 0);
    acc[1][0] = __builtin_amdgcn_mfma_f32_16x16x32_f16(a1, b0, acc[1][0], 0, 0, 0);
    acc[1][1] = __builtin_amdgcn_mfma_f32_16x16x32_f16(a1, b1, acc[1][1], 0, 0, 0);
  }
  for (int mi = 0; mi < 2; ++mi)
    for (int ni = 0; ni < 2; ++ni)
      for (int r = 0; r < 4; ++r) {
        int m = m0 + wm * 32 + mi * 16 + q * 4 + r;
        int n = n0 + wn * 32 + ni * 16 + c;
        int dir = n >= H3_;
        int nn = n - dir * H3_;
        float bv = dir ? bias_b[nn] : bias_f[nn];
        float vv = acc[mi][ni][r] + bv;
        int s = m & (S_ - 1), bb = m >> 9;
        xw[(((size_t)dir * S_ + s) * B_ + bb) * H3_ + nn] = (_Float16)vv;
      }
}

// ---------------- GRU recurrence (64 chains, streamed fp16 weights) ----------------
#if defined(__has_builtin)
#if __has_builtin(__builtin_amdgcn_fdot2)
#define FDOT2(a, b, c) __builtin_amdgcn_fdot2((a), (b), (c), false)
#endif
#endif
#ifndef FDOT2
static __device__ __forceinline__ float fdot2_sw(half2_t a, half2_t b, float c) {
  return c + (float)a.x * (float)b.x + (float)a.y * (float)b.y;
}
#define FDOT2(a, b, c) fdot2_sw((a), (b), (c))
#endif

__global__ __launch_bounds__(384) void gru_kernel(
    const _Float16* __restrict__ xw,   // [2][512][32][1152]
    const _Float16* __restrict__ Whh,  // [2][48][1152][8]
    const float* __restrict__ bhh_f, const float* __restrict__ bhh_b,
    _Float16* __restrict__ out16) {    // [32][512][768]
  const int dir = blockIdx.x & 1, b = blockIdx.x >> 1;
  const int j = threadIdx.x;
  __shared__ __align__(16) _Float16 hbuf[H_];
  __shared__ float hf[H_];
  const float* bhh = dir ? bhh_b : bhh_f;
  const float br = bhh[j], bz = bhh[H_ + j], bn = bhh[2 * H_ + j];
  const uint4* Wq = (const uint4*)(Whh + (size_t)dir * 48 * H3_ * 8);
  const uint4* hq = (const uint4*)hbuf;
  hf[j] = 0.f;
  hbuf[j] = (_Float16)0.f;
  __syncthreads();
  for (int step = 0; step < S_; ++step) {
    const int t = dir ? (S_ - 1 - step) : step;
    const _Float16* xwp = xw + (((size_t)dir * S_ + t) * B_ + b) * H3_;
    float ar = 0.f, az = 0.f, an = 0.f;
#pragma unroll 4
    for (int k8 = 0; k8 < 48; ++k8) {
      uint4 hv = hq[k8];
      uint4 wr = Wq[k8 * H3_ + j];
      uint4 wz = Wq[k8 * H3_ + H_ + j];
      uint4 wn = Wq[k8 * H3_ + 2 * H_ + j];
      half2_t h0 = __builtin_bit_cast(half2_t, hv.x);
      half2_t h1 = __builtin_bit_cast(half2_t, hv.y);
      half2_t h2 = __builtin_bit_cast(half2_t, hv.z);
      half2_t h3 = __builtin_bit_cast(half2_t, hv.w);
      ar = FDOT2(__builtin_bit_cast(half2_t, wr.x), h0, ar);
      ar = FDOT2(__builtin_bit_cast(half2_t, wr.y), h1, ar);
      ar = FDOT2(__builtin_bit_cast(half2_t, wr.z), h2, ar);
      ar = FDOT2(__builtin_bit_cast(half2_t, wr.w), h3, ar);
      az = FDOT2(__builtin_bit_cast(half2_t, wz.x), h0, az);
      az = FDOT2(__builtin_bit_cast(half2_t, wz.y), h1, az);
      az = FDOT2(__builtin_bit_cast(half2_t, wz.z), h2, az);
      az = FDOT2(__builtin_bit_cast(half2_t, wz.w), h3, az);
      an = FDOT2(__builtin_bit_cast(half2_t, wn.x), h0, an);
      an = FDOT2(__builtin_bit_cast(half2_t, wn.y), h1, an);
      an = FDOT2(__builtin_bit_cast(half2_t, wn.z), h2, an);
      an = FDOT2(__builtin_bit_cast(half2_t, wn.w), h3, an);
    }
    float xr = (float)xwp[j], xz = (float)xwp[H_ + j], xn = (float)xwp[2 * H_ + j];
    float r = 1.f / (1.f + expf(-(xr + ar + br)));
    float z = 1.f / (1.f + expf(-(xz + az + bz)));
    float nv = tanhf(xn + r * (an + bn));
    float hnew = (1.f - z) * nv + z * hf[j];
    __syncthreads();   // all dot-reads of hbuf done before overwrite
    hf[j] = hnew;
    hbuf[j] = (_Float16)hnew;
    out16[((size_t)b * S_ + t) * TWOH_ + dir * H_ + j] = (_Float16)hnew;
    __syncthreads();   // writes visible before next step's dots
  }
}

// ---------------- attention scores: tanh(out@Wattn^T + b) @ ctx ----------------
__global__ __launch_bounds__(256) void attn_score_kernel(
    const _Float16* __restrict__ A /*out16 [16384][768]*/,
    const _Float16* __restrict__ Bm /*Wattn16 [768][768]*/,
    const float* __restrict__ b_attn, const float* __restrict__ ctx,
    float* __restrict__ scores) {
  __shared__ _Float16 As[64][40];
  __shared__ _Float16 Bs[64][40];
  const int m0 = blockIdx.x * 64, n0 = blockIdx.y * 64;
  const int tid = threadIdx.x, lane = tid & 63, w = tid >> 6;
  const int wm = w >> 1, wn = w & 1;
  const int q = lane >> 4, c = lane & 15;
  floatx4 acc[2][2] = {};

  const int t = tid & 127;
  const int srow = t >> 1, skh = (t & 1) * 16;
  const _Float16* gsrc =
      (tid < 128 ? A + (size_t)(m0 + srow) * D_ : Bm + (size_t)(n0 + srow) * D_) + skh;
  _Float16* ldst = (tid < 128) ? &As[srow][skh] : &Bs[srow][skh];

  for (int k0 = 0; k0 < D_; k0 += 32) {
    half8_t v0 = *(const half8_t*)(gsrc + k0);
    half8_t v1 = *(const half8_t*)(gsrc + k0 + 8);
    __syncthreads();
    *(half8_t*)ldst = v0;
    *(half8_t*)(ldst + 8) = v1;
    __syncthreads();
    half8_t a0 = *(const half8_t*)&As[wm * 32 + c][q * 8];
    half8_t a1 = *(const half8_t*)&As[wm * 32 + 16 + c][q * 8];
    half8_t b0 = *(const half8_t*)&Bs[wn * 32 + c][q * 8];
    half8_t b1 = *(const half8_t*)&Bs[wn * 32 + 16 + c][q * 8];
    acc[0][0] = __builtin_amdgcn_mfma_f32_16x16x32_f16(a0, b0, acc[0][0], 0, 0, 0);
    acc[0][1] = __builtin_amdgcn_mfma_f32_16x16x32_f16(a0, b1, acc[0][1], 0, 0, 0);
    acc[1][0] = __builtin_amdgcn_mfma_f32_16x16x32_f16(a1, b0, acc[1][0], 0, 0, 0);
    acc[1][1] = __builtin_amdgcn_mfma_f32_16x16x32_f16(a1, b1, acc[1][1], 0, 0, 0);
  }
  for (int mi = 0; mi < 2; ++mi)
    for (int ni = 0; ni < 2; ++ni)
      for (int r = 0; r < 4; ++r) {
        int n = n0 + wn * 32 + ni * 16 + c;
        float vv = tanhf(acc[mi][ni][r] + b_attn[n]) * ctx[n];
        vv += __shfl_xor(vv, 1);
        vv += __shfl_xor(vv, 2);
        vv += __shfl_xor(vv, 4);
        vv += __shfl_xor(vv, 8);
        if (c == 0) {
          int m = m0 + wm * 32 + mi * 16 + q * 4 + r;
          atomicAdd(&scores[m], vv);
        }
      }
}

// ---------------- softmax over S per batch ----------------
__global__ __launch_bounds__(256) void softmax_kernel(const float* __restrict__ scores,
                                                      float* __restrict__ attn) {
  const int b = blockIdx.x, tid = threadIdx.x;
  __shared__ float red[8];
  float s0 = scores[b * S_ + tid], s1 = scores[b * S_ + 256 + tid];
  float m = fmaxf(s0, s1);
  for (int off = 1; off < 64; off <<= 1) m = fmaxf(m, __shfl_xor(m, off));
  int wv = tid >> 6;
  if ((tid & 63) == 0) red[wv] = m;
  __syncthreads();
  m = fmaxf(fmaxf(red[0], red[1]), fmaxf(red[2], red[3]));
  float e0 = expf(s0 - m), e1 = expf(s1 - m);
  float sum = e0 + e1;
  for (int off = 1; off < 64; off <<= 1) sum += __shfl_xor(sum, off);
  if ((tid & 63) == 0) red[4 + wv] = sum;
  __syncthreads();
  sum = red[4] + red[5] + red[6] + red[7];
  float inv = 1.0f / sum;
  attn[b * S_ + tid] = e0 * inv;
  attn[b * S_ + 256 + tid] = e1 * inv;
}

// ---------------- doc embedding: attn-weighted sum ----------------
__global__ __launch_bounds__(384) void doc_kernel(const float* __restrict__ attn,
                                                  const _Float16* __restrict__ out16,
                                                  float* __restrict__ dout) {
  const int b = blockIdx.x, tid = threadIdx.x;
  __shared__ float at[S_];
  for (int i = tid; i < S_; i += 384) at[i] = attn[b * S_ + i];
  __syncthreads();
  const half2_t* p = (const half2_t*)(out16 + (size_t)b * S_ * TWOH_) + tid;
  float acc0 = 0.f, acc1 = 0.f;
  for (int s = 0; s < S_; ++s) {
    half2_t h = p[(size_t)s * (TWOH_ / 2)];
    float wgt = at[s];
    acc0 += wgt * (float)h.x;
    acc1 += wgt * (float)h.y;
  }
  dout[b * TWOH_ + tid * 2] = acc0;
  dout[b * TWOH_ + tid * 2 + 1] = acc1;
}

// ---------------- host ----------------
extern "C" void kernel_launch(void* const* d_in, const int* in_sizes, int n_in,
                              void* d_out, int out_size, void* d_ws, size_t ws_size,
                              hipStream_t stream) {
  const float* ip     = (const float*)d_in[0];
  const float* W_ih_f = (const float*)d_in[1];
  const float* W_hh_f = (const float*)d_in[2];
  const float* b_ih_f = (const float*)d_in[3];
  const float* b_hh_f = (const float*)d_in[4];
  const float* W_ih_b = (const float*)d_in[5];
  const float* W_hh_b = (const float*)d_in[6];
  const float* b_ih_b = (const float*)d_in[7];
  const float* b_hh_b = (const float*)d_in[8];
  const float* W_attn = (const float*)d_in[9];
  const float* b_attn = (const float*)d_in[10];
  const float* context = (const float*)d_in[11];
  float* doc = (float*)d_out;

  char* ws = (char*)d_ws;
  size_t off = 0;
  auto alloc = [&](size_t bytes) {
    char* p = ws + off;
    off += (bytes + 255) & ~(size_t)255;
    return p;
  };
  _Float16* ip16    = (_Float16*)alloc((size_t)M_ * D_ * 2);     // 25.2 MB
  _Float16* Wih16   = (_Float16*)alloc((size_t)N2_ * D_ * 2);    // 3.5 MB
  _Float16* Whh16   = (_Float16*)alloc((size_t)2 * 48 * H3_ * 8 * 2); // 1.8 MB
  _Float16* Wattn16 = (_Float16*)alloc((size_t)TWOH_ * TWOH_ * 2);    // 1.2 MB
  _Float16* xw      = (_Float16*)alloc((size_t)2 * S_ * B_ * H3_ * 2); // 75.5 MB
  _Float16* out16   = (_Float16*)alloc((size_t)B_ * S_ * TWOH_ * 2);   // 25.2 MB
  float* scores     = (float*)alloc((size_t)M_ * 4);
  float* attn       = (float*)alloc((size_t)M_ * 4);

  // 1. converts / packs
  cvt_f32_f16_kernel<<<(M_ * D_ / 4 + 255) / 256, 256, 0, stream>>>(ip, ip16, M_ * D_ / 4);
  cvt_f32_f16_kernel<<<(H3_ * D_ / 4 + 255) / 256, 256, 0, stream>>>(W_ih_f, Wih16, H3_ * D_ / 4);
  cvt_f32_f16_kernel<<<(H3_ * D_ / 4 + 255) / 256, 256, 0, stream>>>(W_ih_b, Wih16 + (size_t)H3_ * D_, H3_ * D_ / 4);
  cvt_f32_f16_kernel<<<(TWOH_ * TWOH_ / 4 + 255) / 256, 256, 0, stream>>>(W_attn, Wattn16, TWOH_ * TWOH_ / 4);
  pack_whh_kernel<<<(2 * H3_ * H_ + 255) / 256, 256, 0, stream>>>(W_hh_f, W_hh_b, Whh16);

  // 2. input projection GEMM
  gemm_xw_kernel<<<dim3(M_ / 64, N2_ / 64), 256, 0, stream>>>(ip16, Wih16, b_ih_f, b_ih_b, xw);

  // 3. recurrence (64 chains)
  gru_kernel<<<64, 384, 0, stream>>>(xw, Whh16, b_hh_f, b_hh_b, out16);

  // 4. attention scores
  hipMemsetAsync(scores, 0, (size_t)M_ * 4, stream);
  attn_score_kernel<<<dim3(M_ / 64, TWOH_ / 64), 256, 0, stream>>>(out16, Wattn16, b_attn, context, scores);

  // 5. softmax + weighted sum
  softmax_kernel<<<B_, 256, 0, stream>>>(scores, attn);
  doc_kernel<<<B_, 384, 0, stream>>>(attn, out16, doc);
}